// Round 1
// baseline (471.963 us; speedup 1.0000x reference)
//
#include <hip/hip_runtime.h>
#include <cstdint>
#include <cstddef>

#define NE 16
#define TOPK 6
#define HID 1024
#define NTOK 8192
#define EPSF 1e-10f

typedef short bf16x8 __attribute__((ext_vector_type(8)));
typedef float f32x4 __attribute__((ext_vector_type(4)));

__device__ __forceinline__ unsigned int f2bf_rne(float f) {
  union { float f; unsigned int u; } v;
  v.f = f;
  return (v.u + 0x7FFFu + ((v.u >> 16) & 1u)) >> 16;
}

__device__ __forceinline__ void load_lds16(const void* g, void* l) {
  __builtin_amdgcn_global_load_lds(
      (const __attribute__((address_space(1))) void*)g,
      (__attribute__((address_space(3))) void*)l, 16, 0, 0);
}

// ---------------- router: logits -> softmax -> top6 -> folded gates ----------
// gate_final[t,e] = softmax_prob/s = q_e/s_top (algebra: the /(s+EPS) renorm and
// the /acc division cancel). eps term = EPS * s/(s+EPS), added in GEMM epilogue.
__global__ __launch_bounds__(256) void router_kernel(
    const float* __restrict__ tokens, const float* __restrict__ rw,
    const float* __restrict__ rb, float* __restrict__ gates,
    float* __restrict__ epst) {
  __shared__ float s_rw[NE * HID];
  const int tid = threadIdx.x;
  const int wv = tid >> 6;
  const int lane = tid & 63;
  const int token = blockIdx.x * 4 + wv;

  for (int i = tid; i < NE * HID / 4; i += 256)
    ((float4*)s_rw)[i] = ((const float4*)rw)[i];
  __syncthreads();

  const float* xp = tokens + (size_t)token * HID;
  float x[16];
#pragma unroll
  for (int j = 0; j < 16; ++j) x[j] = xp[lane + 64 * j];

  float lg[NE];
#pragma unroll
  for (int e = 0; e < NE; ++e) {
    const float* w = s_rw + e * HID;
    float p = 0.f;
#pragma unroll
    for (int j = 0; j < 16; ++j) p += x[j] * w[lane + 64 * j];
    lg[e] = p;
  }
  // butterfly reduce all 16 logits across the 64-lane wave
#pragma unroll
  for (int m = 1; m < 64; m <<= 1) {
#pragma unroll
    for (int e = 0; e < NE; ++e) lg[e] += __shfl_xor(lg[e], m);
  }
  float mx = -1e30f;
#pragma unroll
  for (int e = 0; e < NE; ++e) {
    lg[e] += rb[e];
    mx = fmaxf(mx, lg[e]);
  }
  float q[NE];
  float s_all = 0.f;
#pragma unroll
  for (int e = 0; e < NE; ++e) {
    q[e] = expf(lg[e] - mx);
    s_all += q[e];
  }
  unsigned sel = 0;
  float s_top = 0.f;
  for (int k = 0; k < TOPK; ++k) {
    float best = -1.f;
    int bi = 0;
#pragma unroll
    for (int e = 0; e < NE; ++e) {
      bool taken = (sel >> e) & 1u;
      if (!taken && q[e] > best) { best = q[e]; bi = e; }
    }
    sel |= 1u << bi;
    s_top += best;
  }
  if (lane < NE) {
    float g = ((sel >> lane) & 1u) ? q[lane] / s_top : 0.f;
    gates[(size_t)token * NE + lane] = g;
  }
  if (lane == 32) {
    float s = s_top / s_all;
    epst[token] = EPSF * (s / (s + EPSF));
  }
}

// ---------------- X fp32 -> bf16 (row-major [t][k]) --------------------------
__global__ __launch_bounds__(256) void cvt_x_kernel(
    const float* __restrict__ x, uint32_t* __restrict__ xb) {
  const size_t i = ((size_t)blockIdx.x * 256 + threadIdx.x) * 8;
  const float4 a = *(const float4*)(x + i);
  const float4 b = *(const float4*)(x + i + 4);
  uint4 o;
  o.x = f2bf_rne(a.x) | (f2bf_rne(a.y) << 16);
  o.y = f2bf_rne(a.z) | (f2bf_rne(a.w) << 16);
  o.z = f2bf_rne(b.x) | (f2bf_rne(b.y) << 16);
  o.w = f2bf_rne(b.z) | (f2bf_rne(b.w) << 16);
  *(uint4*)(xb + i / 2) = o;
}

// ---------------- W fp32 [e][k][n] -> bf16 transposed [e][n][k] --------------
__global__ __launch_bounds__(256) void cvt_wt_kernel(
    const float* __restrict__ w, unsigned short* __restrict__ wt) {
  __shared__ float tile[64][65];  // +1 pad: conflict-free transpose
  const int kt = blockIdx.x * 64;
  const int nt = blockIdx.y * 64;
  const int e = blockIdx.z;
  const int tr = threadIdx.x >> 6;  // 0..3
  const int tc = threadIdx.x & 63;
  const float* wp = w + (size_t)e * HID * HID;
#pragma unroll
  for (int r = 0; r < 64; r += 4)
    tile[r + tr][tc] = wp[(size_t)(kt + r + tr) * HID + nt + tc];
  __syncthreads();
  unsigned short* wo = wt + (size_t)e * HID * HID;
#pragma unroll
  for (int c = 0; c < 64; c += 4)
    wo[(size_t)(nt + c + tr) * HID + kt + tc] =
        (unsigned short)f2bf_rne(tile[tc][c + tr]);
}

// ---------------- dense gate-weighted expert GEMM (m97 structure) ------------
// out[t0:t0+128, n0:n0+128] = sum_e gate[t,e] * X[t,:] @ W_e[:,n]  + eps[t]
// 4 waves in 2x2, each wave 64x64 via 4x4 frags of 16x16x32 bf16 MFMA.
__global__ __launch_bounds__(256, 2) void moe_gemm_kernel(
    const unsigned short* __restrict__ Xb, const unsigned short* __restrict__ Wt,
    const float* __restrict__ gates, const float* __restrict__ epst,
    float* __restrict__ out) {
  __shared__ unsigned short As[128 * 32];  // [row][k] 64B rows
  __shared__ unsigned short Bs[128 * 32];  // [col][k] 64B rows (W^T layout)
  __shared__ float Gs[128 * NE];
  __shared__ float Es[128];

  const int tid = threadIdx.x;
  const int wv = tid >> 6;
  const int lane = tid & 63;
  const int t0 = blockIdx.x * 128;
  const int n0 = blockIdx.y * 128;
  const int lm = lane & 15;
  const int quad = lane >> 4;
  const int woff_m = (wv & 1) * 64;
  const int woff_n = (wv >> 1) * 64;

  {  // stage gates [128][16] + eps [128] (read only after many barriers)
    const float4* gsrc = (const float4*)(gates + (size_t)t0 * NE);
    float4* gdst = (float4*)Gs;
    gdst[tid] = gsrc[tid];
    gdst[tid + 256] = gsrc[tid + 256];
    if (tid < 128) Es[tid] = epst[t0 + tid];
  }

  // global_load_lds staging: wave w covers rows 32w..32w+31 in 2 issues of
  // 16 rows; lane l -> row base+l/4, 16B chunk l%4. LDS dest = uniform base
  // + lane*16 (hardware), matching the unpadded row-major tile layout.
  const int srow = wv * 32 + (lane >> 2);
  const int schunk = (lane & 3) * 16;
  const char* gA0base = (const char*)Xb + (size_t)(t0 + srow) * (HID * 2) + schunk;
  const char* gA1base = gA0base + 16 * HID * 2;
  const char* gB0base0 = (const char*)Wt + (size_t)(n0 + srow) * (HID * 2) + schunk;
  const char* gB1base0 = gB0base0 + 16 * HID * 2;
  char* const lA0 = (char*)As + (wv * 32) * 64;
  char* const lA1 = lA0 + 16 * 64;
  char* const lB0 = (char*)Bs + (wv * 32) * 64;
  char* const lB1 = lB0 + 16 * 64;

  f32x4 fin[4][4];
#pragma unroll
  for (int i = 0; i < 4; ++i)
#pragma unroll
    for (int j = 0; j < 4; ++j) fin[i][j] = (f32x4){0.f, 0.f, 0.f, 0.f};

  for (int e = 0; e < NE; ++e) {
    f32x4 acc[4][4];
#pragma unroll
    for (int i = 0; i < 4; ++i)
#pragma unroll
      for (int j = 0; j < 4; ++j) acc[i][j] = (f32x4){0.f, 0.f, 0.f, 0.f};

    const char* gA0 = gA0base;
    const char* gA1 = gA1base;
    const char* gB0 = gB0base0 + (size_t)e * (HID * HID * 2);
    const char* gB1 = gB1base0 + (size_t)e * (HID * HID * 2);

    for (int ks = 0; ks < 32; ++ks) {
      __syncthreads();  // previous iter's ds_reads done before overwrite
      load_lds16(gA0, lA0);
      load_lds16(gA1, lA1);
      load_lds16(gB0, lB0);
      load_lds16(gB1, lB1);
      gA0 += 64; gA1 += 64; gB0 += 64; gB1 += 64;
      __syncthreads();  // vmcnt(0) drain -> tiles resident

      bf16x8 a[4], b[4];
#pragma unroll
      for (int i = 0; i < 4; ++i)
        a[i] = *(const bf16x8*)((const char*)As +
                                (woff_m + 16 * i + lm) * 64 + quad * 16);
#pragma unroll
      for (int j = 0; j < 4; ++j)
        b[j] = *(const bf16x8*)((const char*)Bs +
                                (woff_n + 16 * j + lm) * 64 + quad * 16);
#pragma unroll
      for (int i = 0; i < 4; ++i)
#pragma unroll
        for (int j = 0; j < 4; ++j)
          acc[i][j] =
              __builtin_amdgcn_mfma_f32_16x16x32_bf16(a[i], b[j], acc[i][j], 0, 0, 0);
    }
    // fold this expert into the persistent accumulator, scaled by gate(row,e)
#pragma unroll
    for (int i = 0; i < 4; ++i)
#pragma unroll
      for (int r = 0; r < 4; ++r) {
        const int row = woff_m + 16 * i + quad * 4 + r;
        const float g = Gs[row * NE + e];
#pragma unroll
        for (int j = 0; j < 4; ++j) fin[i][j][r] += g * acc[i][j][r];
      }
  }

  // epilogue: C/D layout col=lane&15, row=quad*4+reg
#pragma unroll
  for (int i = 0; i < 4; ++i)
#pragma unroll
    for (int r = 0; r < 4; ++r) {
      const int row = woff_m + 16 * i + quad * 4 + r;
      const float ep = Es[row];
      float* orow = out + (size_t)(t0 + row) * HID + n0;
#pragma unroll
      for (int j = 0; j < 4; ++j)
        orow[woff_n + 16 * j + lm] = fin[i][j][r] + ep;
    }
}

extern "C" void kernel_launch(void* const* d_in, const int* in_sizes, int n_in,
                              void* d_out, int out_size, void* d_ws, size_t ws_size,
                              hipStream_t stream) {
  const float* tokens = (const float*)d_in[0];  // [4,2048,1024] f32
  const float* rw = (const float*)d_in[1];      // [16,1024] f32
  const float* rb = (const float*)d_in[2];      // [16] f32
  const float* ew = (const float*)d_in[3];      // [16,1024,1024] f32
  float* out = (float*)d_out;                   // [4,2048,1024] f32

  char* ws = (char*)d_ws;
  unsigned short* Xb = (unsigned short*)(ws);                        // 16 MB bf16 [t][k]
  unsigned short* Wt = (unsigned short*)(ws + ((size_t)16 << 20));   // 32 MB bf16 [e][n][k]
  float* gates = (float*)(ws + ((size_t)48 << 20));                  // 512 KB
  float* epst = (float*)(ws + ((size_t)48 << 20) + (1 << 19));       // 32 KB

  router_kernel<<<dim3(NTOK / 4), dim3(256), 0, stream>>>(tokens, rw, rb, gates, epst);
  cvt_x_kernel<<<dim3(NTOK * HID / (256 * 8)), dim3(256), 0, stream>>>(tokens, (uint32_t*)Xb);
  cvt_wt_kernel<<<dim3(HID / 64, HID / 64, NE), dim3(256), 0, stream>>>(ew, Wt);
  moe_gemm_kernel<<<dim3(NTOK / 128, HID / 128), dim3(256), 0, stream>>>(Xb, Wt, gates, epst, out);
}